// Round 17
// baseline (350.106 us; speedup 1.0000x reference)
//
#include <hip/hip_runtime.h>

#define NN 50000
#define NE 1600000
#define EP (NE + NN)          // edges + self loops = 1,650,000
#define D 128
#define H 4
#define NEG 0.2f
#define LN_EPS 1e-5f
#define NBUCK 49              // dst >> 10 buckets
#define BCAP 40960            // fixed binned capacity per bucket (max ~34.5K used)
#define BCAPC 49152           // fixed csr capacity per bucket (count + 8-pad <= 42.7K)
#define CHUNK 4096

typedef _Float16 f16;
typedef _Float16 half8 __attribute__((ext_vector_type(8)));
typedef _Float16 half2v __attribute__((ext_vector_type(2)));
typedef float f32x4v __attribute__((ext_vector_type(4)));
typedef unsigned short u16;
typedef unsigned int u32;

static __device__ __forceinline__ float leakyf(float v) { return fmaxf(v, NEG * v); }

// monotone float -> unsigned key (0 == -inf-ish identity for atomicMax)
static __device__ __forceinline__ u32 ukey(float v) {
    int b = __float_as_int(v);
    return (u32)(b >= 0 ? (b | 0x80000000) : ~b);
}
static __device__ __forceinline__ float udec(u32 u) {
    return __int_as_float((u & 0x80000000u) ? (int)(u & 0x7fffffffu) : ~(int)u);
}

// ---- fat kernel: edge binning  ||  wt conversion  ||  ws16  ||  input proj ----
#define BIN_BLKS 403                    // ceil(EP / CHUNK)
#define WT_BLKS 192                     // 3*D*D / 256
#define WS_BLKS 24                      // 3*16*D / 256
#define KIN_BLKS 3125                   // NN*D/8 / 256
__global__ __launch_bounds__(256) void k_binfat(
        const int* __restrict__ ei, int* __restrict__ gcur, u32* __restrict__ binned,
        const float* __restrict__ w0, const float* __restrict__ w1,
        const float* __restrict__ w2, f16* __restrict__ wt,
        const float* __restrict__ as0, const float* __restrict__ ad0,
        const float* __restrict__ as1, const float* __restrict__ ad1,
        const float* __restrict__ as2, const float* __restrict__ ad2,
        f16* __restrict__ ws16,
        const float* __restrict__ x, const float* __restrict__ w_in,
        const float* __restrict__ b_in, f16* __restrict__ h16) {
    __shared__ u32 pk[CHUNK];
    __shared__ int hist[NBUCK], base[NBUCK], lcur[NBUCK];
    int tid = threadIdx.x;
    int bid = blockIdx.x;

    if (bid < BIN_BLKS) {
        int cbase = bid * CHUNK;
        if (tid < NBUCK) hist[tid] = 0;
        __syncthreads();
#pragma unroll
        for (int j = 0; j < CHUNK / 256; j++) {
            int k = cbase + j * 256 + tid;
            u32 v = 0xFFFFFFFFu;
            if (k < EP) {
                int src, dst;
                if (k < NE) { src = ei[k]; dst = ei[NE + k]; }
                else        { src = k - NE; dst = src; }
                v = ((u32)dst << 16) | (u32)src;
                atomicAdd(&hist[dst >> 10], 1);
            }
            pk[j * 256 + tid] = v;
        }
        __syncthreads();
        if (tid < NBUCK) {
            base[tid] = atomicAdd(&gcur[tid], hist[tid]);
            lcur[tid] = 0;
        }
        __syncthreads();
#pragma unroll
        for (int j = 0; j < CHUNK / 256; j++) {
            u32 v = pk[j * 256 + tid];
            if (v != 0xFFFFFFFFu) {
                int b = v >> 26;  // (v>>16)>>10
                int pos = base[b] + atomicAdd(&lcur[b], 1);
                binned[(size_t)b * BCAP + pos] = v;
            }
        }
        return;
    }
    if (bid < BIN_BLKS + WT_BLKS) {
        int u = (bid - BIN_BLKS) * 256 + tid;          // < 3*D*D
        int l = u / (D * D), rem = u % (D * D);
        int k = rem >> 7, c = rem & 127;
        const float* w = (l == 0) ? w0 : (l == 1) ? w1 : w2;
        wt[l * D * D + c * D + k] = (f16)w[rem];
        return;
    }
    if (bid < BIN_BLKS + WT_BLKS + WS_BLKS) {
        int v = (bid - BIN_BLKS - WT_BLKS) * 256 + tid;   // < 3*16*D
        int l = v / (16 * D), rem = v % (16 * D);
        int c = rem >> 7, k = rem & 127;
        f16 out = (f16)0.f;
        if (c < 8) {
            int head = c >> 1;
            const float* w = (l == 0) ? w0 : (l == 1) ? w1 : w2;
            const float* av = (c & 1) ? ((l == 0) ? ad0 : (l == 1) ? ad1 : ad2)
                                      : ((l == 0) ? as0 : (l == 1) ? as1 : as2);
            float s = 0.f;
#pragma unroll
            for (int j = 0; j < 32; j++)
                s = fmaf(w[k * D + head * 32 + j], av[head * 32 + j], s);
            out = (f16)s;
        }
        ws16[l * 16 * D + c * D + k] = out;
        return;
    }
    // input projection: 8 dims per thread
    int gid = (bid - BIN_BLKS - WT_BLKS - WS_BLKS) * 256 + tid;   // < NN*D/8
    int n = gid >> 4;
    int d0 = (gid & 15) << 3;
    const float* xr = x + n * 5;
    float x0 = xr[0], x1 = xr[1], x2 = xr[2], x3 = xr[3], x4 = xr[4];
    half8 hv;
#pragma unroll
    for (int j = 0; j < 8; j++) {
        int d = d0 + j;
        float acc = b_in[d];
        acc = fmaf(x0, w_in[0 * D + d], acc);
        acc = fmaf(x1, w_in[1 * D + d], acc);
        acc = fmaf(x2, w_in[2 * D + d], acc);
        acc = fmaf(x3, w_in[3 * D + d], acc);
        acc = fmaf(x4, w_in[4 * D + d], acc);
        hv[j] = (f16)acc;
    }
    *(half8*)&h16[(size_t)n * D + d0] = hv;
}

// ---- per-bucket CSR build: LDS histogram + scan + cursor placement ----
__global__ __launch_bounds__(1024) void k_build(const int* __restrict__ gcur,
                                                const u32* __restrict__ binned,
                                                int2* __restrict__ rps,
                                                u16* __restrict__ csr) {
    __shared__ int hist[1024];
    __shared__ int sm[1024];
    int tid = threadIdx.x;
    int b = blockIdx.x;
    hist[tid] = 0;
    __syncthreads();
    int cnt = gcur[b];
    const u32* bb = binned + (size_t)b * BCAP;
    for (int i = tid; i < cnt; i += 1024)
        atomicAdd(&hist[(bb[i] >> 16) & 1023], 1);
    __syncthreads();
    int d = hist[tid];
    int pd = (d + 7) & ~7;
    sm[tid] = pd;
    __syncthreads();
    for (int off = 1; off < 1024; off <<= 1) {
        int t = (tid >= off) ? sm[tid - off] : 0;
        __syncthreads();
        sm[tid] += t;
        __syncthreads();
    }
    int basep = b * BCAPC + sm[tid] - pd;
    int node = (b << 10) + tid;
    if (node < NN) rps[node] = make_int2(basep, basep + pd);
    for (int j = d; j < pd; ++j) csr[basep + j] = 0xFFFFu;
    __syncthreads();
    hist[tid] = basep;        // reuse as per-node cursor
    __syncthreads();
    for (int i = tid; i < cnt; i += 1024) {
        u32 v = bb[i];
        int pos = atomicAdd(&hist[(v >> 16) & 1023], 1);
        csr[pos] = (u16)(v & 0xFFFFu);
    }
}

// --- MFMA GEMM: xh = h16 @ W16; als/ald via extra MFMA tile (ws); global max ---
// 2 A-tiles (32 nodes) per wave share B-frags.
__global__ __launch_bounds__(256) void k_gemm(const f16* __restrict__ h16,
                                              const f16* __restrict__ wt,
                                              const f16* __restrict__ ws16,
                                              f16* __restrict__ xh,
                                              float* __restrict__ als,
                                              float* __restrict__ ald,
                                              u32* __restrict__ gmaxk) {
    __shared__ u32 sgk[4];
    if (threadIdx.x < 4) sgk[threadIdx.x] = 0u;
    int wid = threadIdx.x >> 6;
    int lane = threadIdx.x & 63;
    int wbase = blockIdx.x * 128 + wid * 32;
    int r = lane & 15;
    int g = lane >> 4;

    int arow0 = wbase + r;      if (arow0 >= NN) arow0 = NN - 1;
    int arow1 = wbase + 16 + r; if (arow1 >= NN) arow1 = NN - 1;
    const f16* a0p = h16 + (size_t)arow0 * D + g * 8;
    const f16* a1p = h16 + (size_t)arow1 * D + g * 8;

    f32x4v acc0[8], acc1[8], al0, al1;
#pragma unroll
    for (int nt = 0; nt < 8; nt++) {
        acc0[nt] = (f32x4v){0.f, 0.f, 0.f, 0.f};
        acc1[nt] = (f32x4v){0.f, 0.f, 0.f, 0.f};
    }
    al0 = (f32x4v){0.f, 0.f, 0.f, 0.f};
    al1 = (f32x4v){0.f, 0.f, 0.f, 0.f};

#pragma unroll
    for (int ks = 0; ks < 4; ks++) {
        half8 a0 = *(const half8*)(a0p + ks * 32);
        half8 a1 = *(const half8*)(a1p + ks * 32);
        half8 bal = *(const half8*)(ws16 + (size_t)r * D + ks * 32 + g * 8);
        al0 = __builtin_amdgcn_mfma_f32_16x16x32_f16(a0, bal, al0, 0, 0, 0);
        al1 = __builtin_amdgcn_mfma_f32_16x16x32_f16(a1, bal, al1, 0, 0, 0);
#pragma unroll
        for (int nt = 0; nt < 8; nt++) {
            half8 b = *(const half8*)(wt + (size_t)(nt * 16 + r) * D + ks * 32 + g * 8);
            acc0[nt] = __builtin_amdgcn_mfma_f32_16x16x32_f16(a0, b, acc0[nt], 0, 0, 0);
            acc1[nt] = __builtin_amdgcn_mfma_f32_16x16x32_f16(a1, b, acc1[nt], 0, 0, 0);
        }
    }

#pragma unroll
    for (int rg = 0; rg < 4; rg++) {
        int n0 = wbase + g * 4 + rg;
        if (n0 < NN) {
#pragma unroll
            for (int nt = 0; nt < 8; nt++)
                xh[(size_t)n0 * D + nt * 16 + r] = (f16)acc0[nt][rg];
        }
        int n1 = wbase + 16 + g * 4 + rg;
        if (n1 < NN) {
#pragma unroll
            for (int nt = 0; nt < 8; nt++)
                xh[(size_t)n1 * D + nt * 16 + r] = (f16)acc1[nt][rg];
        }
    }

    float m = -1e30f;
#pragma unroll
    for (int rg = 0; rg < 4; rg++) {
        int n0 = wbase + g * 4 + rg;
        int n1 = wbase + 16 + g * 4 + rg;
        float v0 = al0[rg], v1 = al1[rg];
        if (r < 8) {
            int hh = r >> 1;
            if (r & 1) {
                if (n0 < NN) ald[n0 * H + hh] = v0;
                if (n1 < NN) ald[n1 * H + hh] = v1;
            } else {
                if (n0 < NN) als[n0 * H + hh] = v0;
                if (n1 < NN) als[n1 * H + hh] = v1;
                m = fmaxf(m, fmaxf(v0, v1));   // clamped dup rows still valid for max
            }
        }
    }
    m = fmaxf(m, __shfl_xor(m, 16));
    m = fmaxf(m, __shfl_xor(m, 32));
    __syncthreads();
    if (lane < 8 && !(r & 1)) atomicMax(&sgk[r >> 1], ukey(m));
    __syncthreads();
    if (threadIdx.x < 4) atomicMax(&gmaxk[threadIdx.x], sgk[threadIdx.x]);
}

// ---- fused aggregation, 8 edges/iter, ping-pong 2-group pipeline ----
// lane = slot(2b) | q(4b): slot = edge slot, q -> dims q*8..q*8+7, head = q>>2
__global__ __launch_bounds__(256) void k_agg(const f16* __restrict__ xh,
                                             const float* __restrict__ als,
                                             const float* __restrict__ ald,
                                             const u32* __restrict__ gmaxk,
                                             const int2* __restrict__ rps,
                                             const u16* __restrict__ csr,
                                             const float* __restrict__ cb,
                                             const float* __restrict__ gamma,
                                             const float* __restrict__ beta,
                                             f16* __restrict__ h16,
                                             float* __restrict__ hout, int do_relu) {
    int node = blockIdx.x * 4 + (threadIdx.x >> 6);
    if (node >= NN) return;
    int lane = threadIdx.x & 63;
    int slot = lane >> 4;
    int q = lane & 15;
    int head = q >> 2;
    unsigned qo = q * 8;

    int2 se = rps[node];
    int start = se.x, end = se.y;

    float adH = ald[node * H + head];
    float mH = leakyf(udec(gmaxk[head]) + adH);   // upper bound on segment max

    float acc[8];
#pragma unroll
    for (int j = 0; j < 8; j++) acc[j] = 0.f;
    float den = 0.f;

    int sh = (slot & 1) << 4;
    bool hiw = (slot & 2) != 0;

    bool v0A, v1A, v0B, v1B;
    float al0A, al1A, al0B, al1B;
    half8 p0A, p1A, p0B, p1B;

#define LOADG(S, E)                                                           \
    {                                                                         \
        uint4 cw = *(const uint4*)(csr + (E));                                \
        unsigned dw0 = hiw ? cw.y : cw.x;                                     \
        unsigned dw1 = hiw ? cw.w : cw.z;                                     \
        unsigned s0 = (dw0 >> sh) & 0xffffu;                                  \
        unsigned s1 = (dw1 >> sh) & 0xffffu;                                  \
        v0##S = s0 != 0xffffu;                                                \
        v1##S = s1 != 0xffffu;                                                \
        unsigned sc0 = v0##S ? s0 : 0u;                                       \
        unsigned sc1 = v1##S ? s1 : 0u;                                       \
        al0##S = als[sc0 * 4u + (unsigned)head];                              \
        al1##S = als[sc1 * 4u + (unsigned)head];                              \
        p0##S = *(const half8*)(xh + sc0 * 128u + qo);                        \
        p1##S = *(const half8*)(xh + sc1 * 128u + qo);                        \
    }

#define CONSUME(S)                                                            \
    {                                                                         \
        float ev0 = v0##S ? __expf(leakyf(al0##S + adH) - mH) : 0.f;          \
        float ev1 = v1##S ? __expf(leakyf(al1##S + adH) - mH) : 0.f;          \
        den += ev0 + ev1;                                                     \
        _Pragma("unroll")                                                     \
        for (int j = 0; j < 8; j++)                                           \
            acc[j] = fmaf(ev0, (float)p0##S[j],                               \
                          fmaf(ev1, (float)p1##S[j], acc[j]));                \
    }

    int n8 = (end - start) >> 3;     // >= 1 (self loop)
    int e1 = start + 8;
    LOADG(A, start)
    int rem = n8;
    while (rem >= 2) {
        LOADG(B, e1) e1 += 8;
        CONSUME(A)
        if (rem >= 3) { LOADG(A, e1) e1 += 8; }
        CONSUME(B)
        rem -= 2;
    }
    if (rem & 1) CONSUME(A)
#undef LOADG
#undef CONSUME

    // reduce edge slots (lanes l, l^16, l^32, l^48 share the same dims)
    den += __shfl_xor(den, 16);
    den += __shfl_xor(den, 32);
#pragma unroll
    for (int j = 0; j < 8; j++) {
        acc[j] += __shfl_xor(acc[j], 16);
        acc[j] += __shfl_xor(acc[j], 32);
    }

    float inv_den = 1.f / (den + 1e-16f);
    float o[8];
    const float4* cb4 = (const float4*)(cb + q * 8);
    float4 cba = cb4[0], cbb = cb4[1];
    o[0] = fmaf(acc[0], inv_den, cba.x);
    o[1] = fmaf(acc[1], inv_den, cba.y);
    o[2] = fmaf(acc[2], inv_den, cba.z);
    o[3] = fmaf(acc[3], inv_den, cba.w);
    o[4] = fmaf(acc[4], inv_den, cbb.x);
    o[5] = fmaf(acc[5], inv_den, cbb.y);
    o[6] = fmaf(acc[6], inv_den, cbb.z);
    o[7] = fmaf(acc[7], inv_den, cbb.w);

    // LayerNorm stats: each lane holds 8 dims; q-lanes 0..15 cover all 128
    float s = 0.f;
#pragma unroll
    for (int j = 0; j < 8; j++) s += o[j];
#pragma unroll
    for (int off = 1; off < 16; off <<= 1) s += __shfl_xor(s, off);
    float mean = s * (1.f / 128.f);
    float v = 0.f;
    float c[8];
#pragma unroll
    for (int j = 0; j < 8; j++) { c[j] = o[j] - mean; v = fmaf(c[j], c[j], v); }
#pragma unroll
    for (int off = 1; off < 16; off <<= 1) v += __shfl_xor(v, off);
    float inv = rsqrtf(v * (1.f / 128.f) + LN_EPS);

    // each lane writes dims q*8 + slot*2 + {0,1}
    int dim = q * 8 + slot * 2;
    float2 g2 = *(const float2*)(gamma + dim);
    float2 b2 = *(const float2*)(beta + dim);
    float r0 = c[slot * 2] * inv * g2.x + b2.x;
    float r1 = c[slot * 2 + 1] * inv * g2.y + b2.y;
    if (do_relu) { r0 = fmaxf(r0, 0.f); r1 = fmaxf(r1, 0.f); }
    half2v hv16 = *(const half2v*)&h16[(size_t)node * D + dim];
    float n0 = (float)hv16[0] + r0;
    float n1 = (float)hv16[1] + r1;
    if (do_relu) {
        half2v h2; h2[0] = (f16)n0; h2[1] = (f16)n1;
        *(half2v*)&h16[(size_t)node * D + dim] = h2;
    } else {
        *(float2*)&hout[(size_t)node * D + dim] = (float2){n0, n1};
    }
}

// ------------------------- launch -------------------------
extern "C" void kernel_launch(void* const* d_in, const int* in_sizes, int n_in,
                              void* d_out, int out_size, void* d_ws, size_t ws_size,
                              hipStream_t stream) {
    const float* x    = (const float*)d_in[0];
    const float* w_in = (const float*)d_in[1];
    const float* b_in = (const float*)d_in[2];
    const int*   ei   = (const int*)d_in[21];
    float* hout = (float*)d_out;

    char* w = (char*)d_ws;
    u32* gmaxk  = (u32*)w;   w += 64;
    int* gcur   = (int*)w;   w += 256;
    int2* rps   = (int2*)w;  w += (size_t)NN * 8;
    u16* csr    = (u16*)w;   w += (size_t)NBUCK * BCAPC * 2;
    f16* h16    = (f16*)w;   w += (size_t)NN * D * 2;
    f16* xh     = (f16*)w;   w += (size_t)NN * D * 2;
    f16* wt     = (f16*)w;   w += (size_t)3 * D * D * 2;
    f16* ws16   = (f16*)w;   w += (size_t)3 * 16 * D * 2;
    float* als  = (float*)w; w += (size_t)NN * H * 4;
    float* ald  = (float*)w; w += (size_t)NN * H * 4;
    u32* binned = (u32*)xh;  // xh first written by k_gemm L0, AFTER k_build consumed binned

    // zero gmaxk (unsigned-key identity) + gcur in one async memset
    hipMemsetAsync(d_ws, 0, 320, stream);
    k_binfat<<<BIN_BLKS + WT_BLKS + WS_BLKS + KIN_BLKS, 256, 0, stream>>>(
        ei, gcur, binned,
        (const float*)d_in[3], (const float*)d_in[9], (const float*)d_in[15], wt,
        (const float*)d_in[4], (const float*)d_in[5],
        (const float*)d_in[10], (const float*)d_in[11],
        (const float*)d_in[16], (const float*)d_in[17], ws16,
        x, w_in, b_in, h16);
    k_build<<<NBUCK, 1024, 0, stream>>>(gcur, binned, rps, csr);

    for (int L = 0; L < 3; ++L) {
        const float* cb   = (const float*)d_in[6 + 6 * L];
        const float* g    = (const float*)d_in[7 + 6 * L];
        const float* lb   = (const float*)d_in[8 + 6 * L];
        k_gemm<<<(NN + 127) / 128, 256, 0, stream>>>(h16, wt + (size_t)L * D * D,
                                                     ws16 + (size_t)L * 16 * D,
                                                     xh, als, ald, gmaxk + 4 * L);
        k_agg<<<(NN + 3) / 4, 256, 0, stream>>>(xh, als, ald, gmaxk + 4 * L, rps, csr,
                                                cb, g, lb, h16, hout, L < 2 ? 1 : 0);
    }
}

// Round 18
// 345.413 us; speedup vs baseline: 1.0136x; 1.0136x over previous
//
#include <hip/hip_runtime.h>

#define NN 50000
#define NE 1600000
#define EP (NE + NN)          // edges + self loops = 1,650,000
#define D 128
#define H 4
#define NEG 0.2f
#define LN_EPS 1e-5f
#define NBUCK 49              // dst >> 10 buckets
#define BCAP 40960            // fixed binned capacity per bucket (max ~34.5K used)
#define BCAPC 49152           // fixed csr capacity per bucket (count + 8-pad <= 42.7K)
#define CHUNK 4096

typedef _Float16 f16;
typedef _Float16 half8 __attribute__((ext_vector_type(8)));
typedef _Float16 half2v __attribute__((ext_vector_type(2)));
typedef float f32x4v __attribute__((ext_vector_type(4)));
typedef unsigned short u16;
typedef unsigned int u32;

static __device__ __forceinline__ float leakyf(float v) { return fmaxf(v, NEG * v); }

// monotone float -> unsigned key (0 == identity for atomicMax)
static __device__ __forceinline__ u32 ukey(float v) {
    int b = __float_as_int(v);
    return (u32)(b >= 0 ? (b | 0x80000000) : ~b);
}
static __device__ __forceinline__ float udec(u32 u) {
    return __int_as_float((u & 0x80000000u) ? (int)(u & 0x7fffffffu) : ~(int)u);
}

// ---- fat kernel: edge binning  ||  wt conversion  ||  ws16  ||  input proj ----
#define BIN_BLKS 403                    // ceil(EP / CHUNK)
#define WT_BLKS 192                     // 3*D*D / 256
#define WS_BLKS 24                      // 3*16*D / 256
#define KIN_BLKS 3125                   // NN*D/8 / 256
__global__ __launch_bounds__(256) void k_binfat(
        const int* __restrict__ ei, int* __restrict__ gcur, u32* __restrict__ binned,
        const float* __restrict__ w0, const float* __restrict__ w1,
        const float* __restrict__ w2, f16* __restrict__ wt,
        const float* __restrict__ as0, const float* __restrict__ ad0,
        const float* __restrict__ as1, const float* __restrict__ ad1,
        const float* __restrict__ as2, const float* __restrict__ ad2,
        f16* __restrict__ ws16,
        const float* __restrict__ x, const float* __restrict__ w_in,
        const float* __restrict__ b_in, f16* __restrict__ h16) {
    __shared__ u32 pk[CHUNK];
    __shared__ int hist[NBUCK], base[NBUCK], lcur[NBUCK];
    int tid = threadIdx.x;
    int bid = blockIdx.x;

    if (bid < BIN_BLKS) {
        int cbase = bid * CHUNK;
        if (tid < NBUCK) hist[tid] = 0;
        __syncthreads();
#pragma unroll
        for (int j = 0; j < CHUNK / 256; j++) {
            int k = cbase + j * 256 + tid;
            u32 v = 0xFFFFFFFFu;
            if (k < EP) {
                int src, dst;
                if (k < NE) { src = ei[k]; dst = ei[NE + k]; }
                else        { src = k - NE; dst = src; }
                v = ((u32)dst << 16) | (u32)src;
                atomicAdd(&hist[dst >> 10], 1);
            }
            pk[j * 256 + tid] = v;
        }
        __syncthreads();
        if (tid < NBUCK) {
            base[tid] = atomicAdd(&gcur[tid], hist[tid]);
            lcur[tid] = 0;
        }
        __syncthreads();
#pragma unroll
        for (int j = 0; j < CHUNK / 256; j++) {
            u32 v = pk[j * 256 + tid];
            if (v != 0xFFFFFFFFu) {
                int b = v >> 26;  // (v>>16)>>10
                int pos = base[b] + atomicAdd(&lcur[b], 1);
                binned[(size_t)b * BCAP + pos] = v;
            }
        }
        return;
    }
    if (bid < BIN_BLKS + WT_BLKS) {
        int u = (bid - BIN_BLKS) * 256 + tid;          // < 3*D*D
        int l = u / (D * D), rem = u % (D * D);
        int k = rem >> 7, c = rem & 127;
        const float* w = (l == 0) ? w0 : (l == 1) ? w1 : w2;
        wt[l * D * D + c * D + k] = (f16)w[rem];
        return;
    }
    if (bid < BIN_BLKS + WT_BLKS + WS_BLKS) {
        int v = (bid - BIN_BLKS - WT_BLKS) * 256 + tid;   // < 3*16*D
        int l = v / (16 * D), rem = v % (16 * D);
        int c = rem >> 7, k = rem & 127;
        f16 out = (f16)0.f;
        if (c < 8) {
            int head = c >> 1;
            const float* w = (l == 0) ? w0 : (l == 1) ? w1 : w2;
            const float* av = (c & 1) ? ((l == 0) ? ad0 : (l == 1) ? ad1 : ad2)
                                      : ((l == 0) ? as0 : (l == 1) ? as1 : as2);
            float s = 0.f;
#pragma unroll
            for (int j = 0; j < 32; j++)
                s = fmaf(w[k * D + head * 32 + j], av[head * 32 + j], s);
            out = (f16)s;
        }
        ws16[l * 16 * D + c * D + k] = out;
        return;
    }
    // input projection: 8 dims per thread
    int gid = (bid - BIN_BLKS - WT_BLKS - WS_BLKS) * 256 + tid;   // < NN*D/8
    int n = gid >> 4;
    int d0 = (gid & 15) << 3;
    const float* xr = x + n * 5;
    float x0 = xr[0], x1 = xr[1], x2 = xr[2], x3 = xr[3], x4 = xr[4];
    half8 hv;
#pragma unroll
    for (int j = 0; j < 8; j++) {
        int d = d0 + j;
        float acc = b_in[d];
        acc = fmaf(x0, w_in[0 * D + d], acc);
        acc = fmaf(x1, w_in[1 * D + d], acc);
        acc = fmaf(x2, w_in[2 * D + d], acc);
        acc = fmaf(x3, w_in[3 * D + d], acc);
        acc = fmaf(x4, w_in[4 * D + d], acc);
        hv[j] = (f16)acc;
    }
    *(half8*)&h16[(size_t)n * D + d0] = hv;
}

// ---- per-bucket CSR build: LDS histogram + scan + cursor placement ----
__global__ __launch_bounds__(1024) void k_build(const int* __restrict__ gcur,
                                                const u32* __restrict__ binned,
                                                int2* __restrict__ rps,
                                                u16* __restrict__ csr) {
    __shared__ int hist[1024];
    __shared__ int sm[1024];
    int tid = threadIdx.x;
    int b = blockIdx.x;
    hist[tid] = 0;
    __syncthreads();
    int cnt = gcur[b];
    const u32* bb = binned + (size_t)b * BCAP;
    for (int i = tid; i < cnt; i += 1024)
        atomicAdd(&hist[(bb[i] >> 16) & 1023], 1);
    __syncthreads();
    int d = hist[tid];
    int pd = (d + 7) & ~7;
    sm[tid] = pd;
    __syncthreads();
    for (int off = 1; off < 1024; off <<= 1) {
        int t = (tid >= off) ? sm[tid - off] : 0;
        __syncthreads();
        sm[tid] += t;
        __syncthreads();
    }
    int basep = b * BCAPC + sm[tid] - pd;
    int node = (b << 10) + tid;
    if (node < NN) rps[node] = make_int2(basep, basep + pd);
    for (int j = d; j < pd; ++j) csr[basep + j] = 0xFFFFu;
    __syncthreads();
    hist[tid] = basep;        // reuse as per-node cursor
    __syncthreads();
    for (int i = tid; i < cnt; i += 1024) {
        u32 v = bb[i];
        int pos = atomicAdd(&hist[(v >> 16) & 1023], 1);
        csr[pos] = (u16)(v & 0xFFFFu);
    }
}

// --- MFMA GEMM: xh = h16 @ W16; als/ald via extra MFMA tile (ws); global max ---
// 2 A-tiles (32 nodes) per wave share B-frags.
__global__ __launch_bounds__(256) void k_gemm(const f16* __restrict__ h16,
                                              const f16* __restrict__ wt,
                                              const f16* __restrict__ ws16,
                                              f16* __restrict__ xh,
                                              float* __restrict__ als,
                                              float* __restrict__ ald,
                                              u32* __restrict__ gmaxk) {
    __shared__ u32 sgk[4];
    if (threadIdx.x < 4) sgk[threadIdx.x] = 0u;
    int wid = threadIdx.x >> 6;
    int lane = threadIdx.x & 63;
    int wbase = blockIdx.x * 128 + wid * 32;
    int r = lane & 15;
    int g = lane >> 4;

    int arow0 = wbase + r;      if (arow0 >= NN) arow0 = NN - 1;
    int arow1 = wbase + 16 + r; if (arow1 >= NN) arow1 = NN - 1;
    const f16* a0p = h16 + (size_t)arow0 * D + g * 8;
    const f16* a1p = h16 + (size_t)arow1 * D + g * 8;

    f32x4v acc0[8], acc1[8], al0, al1;
#pragma unroll
    for (int nt = 0; nt < 8; nt++) {
        acc0[nt] = (f32x4v){0.f, 0.f, 0.f, 0.f};
        acc1[nt] = (f32x4v){0.f, 0.f, 0.f, 0.f};
    }
    al0 = (f32x4v){0.f, 0.f, 0.f, 0.f};
    al1 = (f32x4v){0.f, 0.f, 0.f, 0.f};

#pragma unroll
    for (int ks = 0; ks < 4; ks++) {
        half8 a0 = *(const half8*)(a0p + ks * 32);
        half8 a1 = *(const half8*)(a1p + ks * 32);
        half8 bal = *(const half8*)(ws16 + (size_t)r * D + ks * 32 + g * 8);
        al0 = __builtin_amdgcn_mfma_f32_16x16x32_f16(a0, bal, al0, 0, 0, 0);
        al1 = __builtin_amdgcn_mfma_f32_16x16x32_f16(a1, bal, al1, 0, 0, 0);
#pragma unroll
        for (int nt = 0; nt < 8; nt++) {
            half8 b = *(const half8*)(wt + (size_t)(nt * 16 + r) * D + ks * 32 + g * 8);
            acc0[nt] = __builtin_amdgcn_mfma_f32_16x16x32_f16(a0, b, acc0[nt], 0, 0, 0);
            acc1[nt] = __builtin_amdgcn_mfma_f32_16x16x32_f16(a1, b, acc1[nt], 0, 0, 0);
        }
    }

#pragma unroll
    for (int rg = 0; rg < 4; rg++) {
        int n0 = wbase + g * 4 + rg;
        if (n0 < NN) {
#pragma unroll
            for (int nt = 0; nt < 8; nt++)
                xh[(size_t)n0 * D + nt * 16 + r] = (f16)acc0[nt][rg];
        }
        int n1 = wbase + 16 + g * 4 + rg;
        if (n1 < NN) {
#pragma unroll
            for (int nt = 0; nt < 8; nt++)
                xh[(size_t)n1 * D + nt * 16 + r] = (f16)acc1[nt][rg];
        }
    }

    float m = -1e30f;
#pragma unroll
    for (int rg = 0; rg < 4; rg++) {
        int n0 = wbase + g * 4 + rg;
        int n1 = wbase + 16 + g * 4 + rg;
        float v0 = al0[rg], v1 = al1[rg];
        if (r < 8) {
            int hh = r >> 1;
            if (r & 1) {
                if (n0 < NN) ald[n0 * H + hh] = v0;
                if (n1 < NN) ald[n1 * H + hh] = v1;
            } else {
                if (n0 < NN) als[n0 * H + hh] = v0;
                if (n1 < NN) als[n1 * H + hh] = v1;
                m = fmaxf(m, fmaxf(v0, v1));   // clamped dup rows still valid for max
            }
        }
    }
    m = fmaxf(m, __shfl_xor(m, 16));
    m = fmaxf(m, __shfl_xor(m, 32));
    __syncthreads();
    if (lane < 8 && !(r & 1)) atomicMax(&sgk[r >> 1], ukey(m));
    __syncthreads();
    if (threadIdx.x < 4) atomicMax(&gmaxk[threadIdx.x], sgk[threadIdx.x]);
}

// ---- fused aggregation, 8 edges/iter, 1-deep software pipeline ----
// lane = slot(2b) | q(4b): slot = edge slot, q -> dims q*8..q*8+7, head = q>>2
__global__ __launch_bounds__(256) void k_agg(const f16* __restrict__ xh,
                                             const float* __restrict__ als,
                                             const float* __restrict__ ald,
                                             const u32* __restrict__ gmaxk,
                                             const int2* __restrict__ rps,
                                             const u16* __restrict__ csr,
                                             const float* __restrict__ cb,
                                             const float* __restrict__ gamma,
                                             const float* __restrict__ beta,
                                             f16* __restrict__ h16,
                                             float* __restrict__ hout, int do_relu) {
    int node = blockIdx.x * 4 + (threadIdx.x >> 6);
    if (node >= NN) return;
    int lane = threadIdx.x & 63;
    int slot = lane >> 4;
    int q = lane & 15;
    int head = q >> 2;
    unsigned qo = q * 8;

    int2 se = rps[node];
    int start = se.x, end = se.y;

    float adH = ald[node * H + head];
    float mH = leakyf(udec(gmaxk[head]) + adH);   // upper bound on segment max

    float acc[8];
#pragma unroll
    for (int j = 0; j < 8; j++) acc[j] = 0.f;
    float den = 0.f;

    int sh = (slot & 1) << 4;
    bool hiw = (slot & 2) != 0;

    // pipeline prologue: load iteration 0 (deg >= 1 always: self loop)
    uint4 cw = *(const uint4*)(csr + start);
    unsigned dw0 = hiw ? cw.y : cw.x;
    unsigned dw1 = hiw ? cw.w : cw.z;
    unsigned s0 = (dw0 >> sh) & 0xffffu;
    unsigned s1 = (dw1 >> sh) & 0xffffu;
    bool v0 = s0 != 0xffffu;
    bool v1 = s1 != 0xffffu;
    unsigned sc0 = v0 ? s0 : 0u;
    unsigned sc1 = v1 ? s1 : 0u;
    float al0 = als[sc0 * 4u + (unsigned)head];
    float al1 = als[sc1 * 4u + (unsigned)head];
    half8 p0 = *(const half8*)(xh + sc0 * 128u + qo);
    half8 p1 = *(const half8*)(xh + sc1 * 128u + qo);

    for (int e = start; e < end; e += 8) {
        // prefetch iteration i+1 (issue loads before consuming current)
        int en = e + 8;
        bool more = en < end;
        uint4 cwn = *(const uint4*)(csr + (more ? en : e));
        unsigned dw0n = hiw ? cwn.y : cwn.x;
        unsigned dw1n = hiw ? cwn.w : cwn.z;
        unsigned s0n = (dw0n >> sh) & 0xffffu;
        unsigned s1n = (dw1n >> sh) & 0xffffu;
        bool v0n = more && (s0n != 0xffffu);
        bool v1n = more && (s1n != 0xffffu);
        unsigned sc0n = v0n ? s0n : 0u;
        unsigned sc1n = v1n ? s1n : 0u;
        float al0n = als[sc0n * 4u + (unsigned)head];
        float al1n = als[sc1n * 4u + (unsigned)head];
        half8 p0n = *(const half8*)(xh + sc0n * 128u + qo);
        half8 p1n = *(const half8*)(xh + sc1n * 128u + qo);

        // consume iteration i (operands loaded one iteration ago)
        float ev0 = v0 ? __expf(leakyf(al0 + adH) - mH) : 0.f;
        float ev1 = v1 ? __expf(leakyf(al1 + adH) - mH) : 0.f;
        den += ev0 + ev1;
#pragma unroll
        for (int j = 0; j < 8; j++)
            acc[j] = fmaf(ev0, (float)p0[j], fmaf(ev1, (float)p1[j], acc[j]));

        // rotate
        v0 = v0n; v1 = v1n;
        al0 = al0n; al1 = al1n;
        p0 = p0n; p1 = p1n;
    }

    // reduce edge slots (lanes l, l^16, l^32, l^48 share the same dims)
    den += __shfl_xor(den, 16);
    den += __shfl_xor(den, 32);
#pragma unroll
    for (int j = 0; j < 8; j++) {
        acc[j] += __shfl_xor(acc[j], 16);
        acc[j] += __shfl_xor(acc[j], 32);
    }

    float inv_den = 1.f / (den + 1e-16f);
    float o[8];
    const float4* cb4 = (const float4*)(cb + q * 8);
    float4 cba = cb4[0], cbb = cb4[1];
    o[0] = fmaf(acc[0], inv_den, cba.x);
    o[1] = fmaf(acc[1], inv_den, cba.y);
    o[2] = fmaf(acc[2], inv_den, cba.z);
    o[3] = fmaf(acc[3], inv_den, cba.w);
    o[4] = fmaf(acc[4], inv_den, cbb.x);
    o[5] = fmaf(acc[5], inv_den, cbb.y);
    o[6] = fmaf(acc[6], inv_den, cbb.z);
    o[7] = fmaf(acc[7], inv_den, cbb.w);

    // LayerNorm stats: each lane holds 8 dims; q-lanes 0..15 cover all 128
    float s = 0.f;
#pragma unroll
    for (int j = 0; j < 8; j++) s += o[j];
#pragma unroll
    for (int off = 1; off < 16; off <<= 1) s += __shfl_xor(s, off);
    float mean = s * (1.f / 128.f);
    float v = 0.f;
    float c[8];
#pragma unroll
    for (int j = 0; j < 8; j++) { c[j] = o[j] - mean; v = fmaf(c[j], c[j], v); }
#pragma unroll
    for (int off = 1; off < 16; off <<= 1) v += __shfl_xor(v, off);
    float inv = rsqrtf(v * (1.f / 128.f) + LN_EPS);

    // each lane writes dims q*8 + slot*2 + {0,1}
    int dim = q * 8 + slot * 2;
    float2 g2 = *(const float2*)(gamma + dim);
    float2 b2 = *(const float2*)(beta + dim);
    float r0 = c[slot * 2] * inv * g2.x + b2.x;
    float r1 = c[slot * 2 + 1] * inv * g2.y + b2.y;
    if (do_relu) { r0 = fmaxf(r0, 0.f); r1 = fmaxf(r1, 0.f); }
    half2v hv16 = *(const half2v*)&h16[(size_t)node * D + dim];
    float n0 = (float)hv16[0] + r0;
    float n1 = (float)hv16[1] + r1;
    if (do_relu) {
        half2v h2; h2[0] = (f16)n0; h2[1] = (f16)n1;
        *(half2v*)&h16[(size_t)node * D + dim] = h2;
    } else {
        *(float2*)&hout[(size_t)node * D + dim] = (float2){n0, n1};
    }
}

// ------------------------- launch -------------------------
extern "C" void kernel_launch(void* const* d_in, const int* in_sizes, int n_in,
                              void* d_out, int out_size, void* d_ws, size_t ws_size,
                              hipStream_t stream) {
    const float* x    = (const float*)d_in[0];
    const float* w_in = (const float*)d_in[1];
    const float* b_in = (const float*)d_in[2];
    const int*   ei   = (const int*)d_in[21];
    float* hout = (float*)d_out;

    char* w = (char*)d_ws;
    u32* gmaxk  = (u32*)w;   w += 64;
    int* gcur   = (int*)w;   w += 256;
    int2* rps   = (int2*)w;  w += (size_t)NN * 8;
    u16* csr    = (u16*)w;   w += (size_t)NBUCK * BCAPC * 2;
    f16* h16    = (f16*)w;   w += (size_t)NN * D * 2;
    f16* xh     = (f16*)w;   w += (size_t)NN * D * 2;
    f16* wt     = (f16*)w;   w += (size_t)3 * D * D * 2;
    f16* ws16   = (f16*)w;   w += (size_t)3 * 16 * D * 2;
    float* als  = (float*)w; w += (size_t)NN * H * 4;
    float* ald  = (float*)w; w += (size_t)NN * H * 4;
    u32* binned = (u32*)xh;  // xh first written by k_gemm L0, AFTER k_build consumed binned

    // zero gmaxk (unsigned-key identity) + gcur in one async memset
    hipMemsetAsync(d_ws, 0, 320, stream);
    k_binfat<<<BIN_BLKS + WT_BLKS + WS_BLKS + KIN_BLKS, 256, 0, stream>>>(
        ei, gcur, binned,
        (const float*)d_in[3], (const float*)d_in[9], (const float*)d_in[15], wt,
        (const float*)d_in[4], (const float*)d_in[5],
        (const float*)d_in[10], (const float*)d_in[11],
        (const float*)d_in[16], (const float*)d_in[17], ws16,
        x, w_in, b_in, h16);
    k_build<<<NBUCK, 1024, 0, stream>>>(gcur, binned, rps, csr);

    for (int L = 0; L < 3; ++L) {
        const float* cb   = (const float*)d_in[6 + 6 * L];
        const float* g    = (const float*)d_in[7 + 6 * L];
        const float* lb   = (const float*)d_in[8 + 6 * L];
        k_gemm<<<(NN + 127) / 128, 256, 0, stream>>>(h16, wt + (size_t)L * D * D,
                                                     ws16 + (size_t)L * 16 * D,
                                                     xh, als, ald, gmaxk + 4 * L);
        k_agg<<<(NN + 3) / 4, 256, 0, stream>>>(xh, als, ald, gmaxk + 4 * L, rps, csr,
                                                cb, g, lb, h16, hout, L < 2 ? 1 : 0);
    }
}